// Round 4
// baseline (374.884 us; speedup 1.0000x reference)
//
#include <hip/hip_runtime.h>

#define BB 4
#define CC 5
#define HH 200
#define DKk 20
#define DI 400
#define NPOS (BB*CC*HH)   // 4000

// ---------------------------------------------------------------------------
// Kernel 1: projections (all fp32).
//   q/k/v[pos,d] = sum_n X[pos,n,d]*W[n] + b   (N=400, X row stride 20 floats)
//   c[pos,d]     = sum_n cdd[pos,n,d]*W1[n]+b1 (N=20)
// One thread per (tensor,pos,d-quad): 4*4000*5 = 80000 threads.
// Each thread streams float4 (16B) loads, stride 80B; the 5 quad-threads of a
// position cover each 80B row exactly once -> every input byte read once.
// ---------------------------------------------------------------------------
__global__ __launch_bounds__(256) void proj_kernel(
    const float* __restrict__ Q,
    const float* __restrict__ K,
    const float* __restrict__ V,
    const float* __restrict__ cdd,
    const float* __restrict__ W,
    const float* __restrict__ bptr,
    const float* __restrict__ W1,
    const float* __restrict__ b1ptr,
    float* __restrict__ proj)   // [4][NPOS][20] : q,k,v,c
{
    int tau = blockIdx.x * 256 + threadIdx.x;
    if (tau >= 4 * NPOS * 5) return;
    int quad   = tau % 5;
    int pg     = tau / 5;          // 0..15999
    int tensor = pg / NPOS;        // 0..3
    int pos    = pg % NPOS;

    const float* src;
    const float* w;
    float bias;
    int N;
    if (tensor == 0)      { src = Q   + (size_t)pos * (DI * DKk); w = W;  bias = bptr[0];  N = DI; }
    else if (tensor == 1) { src = K   + (size_t)pos * (DI * DKk); w = W;  bias = bptr[0];  N = DI; }
    else if (tensor == 2) { src = V   + (size_t)pos * (DI * DKk); w = W;  bias = bptr[0];  N = DI; }
    else                  { src = cdd + (size_t)pos * (DKk * DKk); w = W1; bias = b1ptr[0]; N = DKk; }

    src += quad * 4;
    float a0 = 0.f, a1 = 0.f, a2 = 0.f, a3 = 0.f;
    #pragma unroll 8
    for (int n = 0; n < N; ++n) {
        float4 x = *reinterpret_cast<const float4*>(src + (size_t)n * DKk);
        float wn = w[n];
        a0 += wn * x.x;
        a1 += wn * x.y;
        a2 += wn * x.z;
        a3 += wn * x.w;
    }
    float4 o; o.x = a0 + bias; o.y = a1 + bias; o.z = a2 + bias; o.w = a3 + bias;
    *reinterpret_cast<float4*>(proj + ((size_t)tensor * NPOS + pos) * DKk + quad * 4) = o;
}

// ---------------------------------------------------------------------------
// Kernel 2: attention. Per (b,c): scores[h,g] = (q[h].k[g] + k[h].c[g])/sqrt(20)
// s = exp(scores). Writes UNNORMALIZED s (fp32) into the attn region of d_out;
// context (normalized with exact fp32 rowsum) -> d_out head.
// Grid: 20 bc * 25 row-tiles = 500 blocks; 256 thr = 8 rows * 32 subs.
// k/c/v tiles of this (b,c) staged in LDS (48 KB fp32).
// ---------------------------------------------------------------------------
__global__ __launch_bounds__(256) void attn_kernel(
    const float* __restrict__ proj,
    float* __restrict__ s_out,     // [NPOS][200] fp32, unnormalized (in d_out)
    float* __restrict__ ctx_out)   // [NPOS][20] fp32 (d_out head)
{
    __shared__ float sk[HH * DKk];
    __shared__ float sc[HH * DKk];
    __shared__ float sv[HH * DKk];

    int bc   = blockIdx.x / 25;
    int tile = blockIdx.x % 25;
    int t    = threadIdx.x;

    const float* kp = proj + ((size_t)1 * NPOS + bc * HH) * DKk;
    const float* vp = proj + ((size_t)2 * NPOS + bc * HH) * DKk;
    const float* cp = proj + ((size_t)3 * NPOS + bc * HH) * DKk;

    for (int i = t; i < HH * DKk / 4; i += 256) {
        reinterpret_cast<float4*>(sk)[i] = reinterpret_cast<const float4*>(kp)[i];
        reinterpret_cast<float4*>(sc)[i] = reinterpret_cast<const float4*>(cp)[i];
        reinterpret_cast<float4*>(sv)[i] = reinterpret_cast<const float4*>(vp)[i];
    }
    __syncthreads();

    int row = t >> 5;            // 0..7
    int sub = t & 31;            // 0..31
    int h   = tile * 8 + row;    // 0..199
    int rowIdx = bc * HH + h;

    const float* qr_p = proj + ((size_t)0 * NPOS + rowIdx) * DKk;
    const float* kr_p = proj + ((size_t)1 * NPOS + rowIdx) * DKk;
    float qr[DKk], kr[DKk];
    #pragma unroll
    for (int i = 0; i < 5; ++i) {
        float4 a = reinterpret_cast<const float4*>(qr_p)[i];
        qr[4*i] = a.x; qr[4*i+1] = a.y; qr[4*i+2] = a.z; qr[4*i+3] = a.w;
        float4 b = reinterpret_cast<const float4*>(kr_p)[i];
        kr[4*i] = b.x; kr[4*i+1] = b.y; kr[4*i+2] = b.z; kr[4*i+3] = b.w;
    }

    const float inv_sqrt = 0.22360679774997896f;  // 1/sqrt(20)
    float ctx[DKk];
    #pragma unroll
    for (int d = 0; d < DKk; ++d) ctx[d] = 0.f;
    float rs = 0.f;

    for (int kk = 0; kk < 7; ++kk) {
        int g = sub + 32 * kk;
        if (g < HH) {
            float dot = 0.f;
            #pragma unroll
            for (int i = 0; i < 5; ++i) {
                float4 kg = reinterpret_cast<const float4*>(sk + g * DKk)[i];
                float4 cg = reinterpret_cast<const float4*>(sc + g * DKk)[i];
                dot += qr[4*i]   * kg.x + qr[4*i+1] * kg.y
                     + qr[4*i+2] * kg.z + qr[4*i+3] * kg.w;
                dot += kr[4*i]   * cg.x + kr[4*i+1] * cg.y
                     + kr[4*i+2] * cg.z + kr[4*i+3] * cg.w;
            }
            float s = __expf(dot * inv_sqrt);
            rs += s;
            s_out[(size_t)rowIdx * HH + g] = s;
            #pragma unroll
            for (int i = 0; i < 5; ++i) {
                float4 vg = reinterpret_cast<const float4*>(sv + g * DKk)[i];
                ctx[4*i]   += s * vg.x;
                ctx[4*i+1] += s * vg.y;
                ctx[4*i+2] += s * vg.z;
                ctx[4*i+3] += s * vg.w;
            }
        }
    }

    // reduce across the 32 subs of this row (lanes contiguous, width=32)
    #pragma unroll
    for (int off = 16; off >= 1; off >>= 1) {
        rs += __shfl_down(rs, (unsigned)off, 32);
        #pragma unroll
        for (int d = 0; d < DKk; ++d)
            ctx[d] += __shfl_down(ctx[d], (unsigned)off, 32);
    }

    if (sub == 0) {
        float invd = 1.0f / (rs + 1e-8f);
        #pragma unroll
        for (int d = 0; d < DKk; ++d)
            ctx_out[(size_t)rowIdx * DKk + d] = ctx[d] * invd;
    }
}

// ---------------------------------------------------------------------------
// Kernel 3: in-place normalize attn rows (fp32). One block (256 thr) per row.
// ---------------------------------------------------------------------------
__global__ __launch_bounds__(256) void norm_kernel(
    float* __restrict__ attn)   // [NPOS][200] fp32, in/out
{
    __shared__ float partial[4];
    __shared__ float inv_sh;
    int row = blockIdx.x;
    int t = threadIdx.x;
    float s = (t < HH) ? attn[(size_t)row * HH + t] : 0.f;
    float v = s;
    #pragma unroll
    for (int off = 32; off >= 1; off >>= 1)
        v += __shfl_down(v, (unsigned)off, 64);
    if ((t & 63) == 0) partial[t >> 6] = v;
    __syncthreads();
    if (t == 0) inv_sh = 1.0f / (partial[0] + partial[1] + partial[2] + partial[3] + 1e-8f);
    __syncthreads();
    if (t < HH)
        attn[(size_t)row * HH + t] = s * inv_sh;
}

extern "C" void kernel_launch(void* const* d_in, const int* in_sizes, int n_in,
                              void* d_out, int out_size, void* d_ws, size_t ws_size,
                              hipStream_t stream) {
    const float* Q   = (const float*)d_in[0];
    const float* K   = (const float*)d_in[1];
    const float* V   = (const float*)d_in[2];
    const float* cdd = (const float*)d_in[3];
    const float* W   = (const float*)d_in[4];
    const float* b   = (const float*)d_in[5];
    const float* W1  = (const float*)d_in[6];
    const float* b1  = (const float*)d_in[7];
    // d_in[8] = d_k (int) — compile-time constant 20

    float* proj = (float*)d_ws;           // 4*4000*20 = 320000 floats = 1.28 MB

    float* out      = (float*)d_out;
    float* ctx_out  = out;                // 80000 fp32 (context)
    float* attn_out = out + 80000;        // 800000 fp32 (attn)

    proj_kernel<<<(4 * NPOS * 5 + 255) / 256, 256, 0, stream>>>(
        Q, K, V, cdd, W, b, W1, b1, proj);
    attn_kernel<<<CC * BB * 25, 256, 0, stream>>>(proj, attn_out, ctx_out);
    norm_kernel<<<NPOS, 256, 0, stream>>>(attn_out);
}

// Round 5
// 373.826 us; speedup vs baseline: 1.0028x; 1.0028x over previous
//
#include <hip/hip_runtime.h>

#define BB 4
#define CC 5
#define HH 200
#define DKk 20
#define DI 400
#define NPOS (BB*CC*HH)   // 4000

// ---------------------------------------------------------------------------
// Kernel 1: projections (all fp32).
//   q/k/v[pos,d] = sum_n X[pos,n,d]*W[n] + b   (N=400, row stride 20 floats)
//   c[pos,d]     = sum_n cdd[pos,n,d]*W1[n]+b1 (N=20)
// One thread per (tensor,pos,d-quad): 4*4000*5 = 80000 threads.
// R4 lesson: VGPR=32 serialized the loads (depth~1, 800 cyc/load). Fix:
// explicit 16-deep load batch into a register array + launch_bounds(256,1)
// so the allocator can hold ~84 VGPRs -> 16 loads in flight per thread.
// In-flight/CU = 4.9 waves * 16KB = 78KB >> 9.2KB needed for HBM saturation.
// ---------------------------------------------------------------------------
__global__ __launch_bounds__(256, 1) void proj_kernel(
    const float* __restrict__ Q,
    const float* __restrict__ K,
    const float* __restrict__ V,
    const float* __restrict__ cdd,
    const float* __restrict__ W,
    const float* __restrict__ bptr,
    const float* __restrict__ W1,
    const float* __restrict__ b1ptr,
    float* __restrict__ proj)   // [4][NPOS][20] : q,k,v,c
{
    int tau = blockIdx.x * 256 + threadIdx.x;
    if (tau >= 4 * NPOS * 5) return;
    int quad   = tau % 5;
    int pg     = tau / 5;          // 0..15999
    int tensor = pg / NPOS;        // 0..3
    int pos    = pg % NPOS;

    float a0 = 0.f, a1 = 0.f, a2 = 0.f, a3 = 0.f;

    if (tensor < 3) {
        const float* base = (tensor == 0) ? Q : (tensor == 1) ? K : V;
        const float* src  = base + (size_t)pos * (DI * DKk) + quad * 4;
        float bias = bptr[0];

        for (int ii = 0; ii < DI; ii += 16) {
            float4 x[16];
            #pragma unroll
            for (int j = 0; j < 16; ++j)
                x[j] = *reinterpret_cast<const float4*>(src + (size_t)(ii + j) * DKk);
            #pragma unroll
            for (int j = 0; j < 16; ++j) {
                float wn = W[ii + j];
                a0 += wn * x[j].x;
                a1 += wn * x[j].y;
                a2 += wn * x[j].z;
                a3 += wn * x[j].w;
            }
        }
        float4 o; o.x = a0 + bias; o.y = a1 + bias; o.z = a2 + bias; o.w = a3 + bias;
        *reinterpret_cast<float4*>(proj + ((size_t)tensor * NPOS + pos) * DKk + quad * 4) = o;
    } else {
        const float* src = cdd + (size_t)pos * (DKk * DKk) + quad * 4;
        float bias = b1ptr[0];
        float4 x[DKk];
        #pragma unroll
        for (int j = 0; j < DKk; ++j)
            x[j] = *reinterpret_cast<const float4*>(src + (size_t)j * DKk);
        #pragma unroll
        for (int j = 0; j < DKk; ++j) {
            float wn = W1[j];
            a0 += wn * x[j].x;
            a1 += wn * x[j].y;
            a2 += wn * x[j].z;
            a3 += wn * x[j].w;
        }
        float4 o; o.x = a0 + bias; o.y = a1 + bias; o.z = a2 + bias; o.w = a3 + bias;
        *reinterpret_cast<float4*>(proj + ((size_t)3 * NPOS + pos) * DKk + quad * 4) = o;
    }
}

// ---------------------------------------------------------------------------
// Kernel 2: attention. Per (b,c): scores[h,g] = (q[h].k[g] + k[h].c[g])/sqrt(20)
// s = exp(scores). Writes UNNORMALIZED s (fp32) into the attn region of d_out;
// context (normalized with exact fp32 rowsum) -> d_out head.
// Grid: 20 bc * 25 row-tiles = 500 blocks; 256 thr = 8 rows * 32 subs.
// ---------------------------------------------------------------------------
__global__ __launch_bounds__(256) void attn_kernel(
    const float* __restrict__ proj,
    float* __restrict__ s_out,     // [NPOS][200] fp32, unnormalized (in d_out)
    float* __restrict__ ctx_out)   // [NPOS][20] fp32 (d_out head)
{
    __shared__ float sk[HH * DKk];
    __shared__ float sc[HH * DKk];
    __shared__ float sv[HH * DKk];

    int bc   = blockIdx.x / 25;
    int tile = blockIdx.x % 25;
    int t    = threadIdx.x;

    const float* kp = proj + ((size_t)1 * NPOS + bc * HH) * DKk;
    const float* vp = proj + ((size_t)2 * NPOS + bc * HH) * DKk;
    const float* cp = proj + ((size_t)3 * NPOS + bc * HH) * DKk;

    for (int i = t; i < HH * DKk / 4; i += 256) {
        reinterpret_cast<float4*>(sk)[i] = reinterpret_cast<const float4*>(kp)[i];
        reinterpret_cast<float4*>(sc)[i] = reinterpret_cast<const float4*>(cp)[i];
        reinterpret_cast<float4*>(sv)[i] = reinterpret_cast<const float4*>(vp)[i];
    }
    __syncthreads();

    int row = t >> 5;            // 0..7
    int sub = t & 31;            // 0..31
    int h   = tile * 8 + row;    // 0..199
    int rowIdx = bc * HH + h;

    const float* qr_p = proj + ((size_t)0 * NPOS + rowIdx) * DKk;
    const float* kr_p = proj + ((size_t)1 * NPOS + rowIdx) * DKk;
    float qr[DKk], kr[DKk];
    #pragma unroll
    for (int i = 0; i < 5; ++i) {
        float4 a = reinterpret_cast<const float4*>(qr_p)[i];
        qr[4*i] = a.x; qr[4*i+1] = a.y; qr[4*i+2] = a.z; qr[4*i+3] = a.w;
        float4 b = reinterpret_cast<const float4*>(kr_p)[i];
        kr[4*i] = b.x; kr[4*i+1] = b.y; kr[4*i+2] = b.z; kr[4*i+3] = b.w;
    }

    const float inv_sqrt = 0.22360679774997896f;  // 1/sqrt(20)
    float ctx[DKk];
    #pragma unroll
    for (int d = 0; d < DKk; ++d) ctx[d] = 0.f;
    float rs = 0.f;

    for (int kk = 0; kk < 7; ++kk) {
        int g = sub + 32 * kk;
        if (g < HH) {
            float dot = 0.f;
            #pragma unroll
            for (int i = 0; i < 5; ++i) {
                float4 kg = reinterpret_cast<const float4*>(sk + g * DKk)[i];
                float4 cg = reinterpret_cast<const float4*>(sc + g * DKk)[i];
                dot += qr[4*i]   * kg.x + qr[4*i+1] * kg.y
                     + qr[4*i+2] * kg.z + qr[4*i+3] * kg.w;
                dot += kr[4*i]   * cg.x + kr[4*i+1] * cg.y
                     + kr[4*i+2] * cg.z + kr[4*i+3] * cg.w;
            }
            float s = __expf(dot * inv_sqrt);
            rs += s;
            s_out[(size_t)rowIdx * HH + g] = s;
            #pragma unroll
            for (int i = 0; i < 5; ++i) {
                float4 vg = reinterpret_cast<const float4*>(sv + g * DKk)[i];
                ctx[4*i]   += s * vg.x;
                ctx[4*i+1] += s * vg.y;
                ctx[4*i+2] += s * vg.z;
                ctx[4*i+3] += s * vg.w;
            }
        }
    }

    // reduce across the 32 subs of this row (lanes contiguous, width=32)
    #pragma unroll
    for (int off = 16; off >= 1; off >>= 1) {
        rs += __shfl_down(rs, (unsigned)off, 32);
        #pragma unroll
        for (int d = 0; d < DKk; ++d)
            ctx[d] += __shfl_down(ctx[d], (unsigned)off, 32);
    }

    if (sub == 0) {
        float invd = 1.0f / (rs + 1e-8f);
        #pragma unroll
        for (int d = 0; d < DKk; ++d)
            ctx_out[(size_t)rowIdx * DKk + d] = ctx[d] * invd;
    }
}

// ---------------------------------------------------------------------------
// Kernel 3: in-place normalize attn rows (fp32). One block (256 thr) per row.
// ---------------------------------------------------------------------------
__global__ __launch_bounds__(256) void norm_kernel(
    float* __restrict__ attn)   // [NPOS][200] fp32, in/out
{
    __shared__ float partial[4];
    __shared__ float inv_sh;
    int row = blockIdx.x;
    int t = threadIdx.x;
    float s = (t < HH) ? attn[(size_t)row * HH + t] : 0.f;
    float v = s;
    #pragma unroll
    for (int off = 32; off >= 1; off >>= 1)
        v += __shfl_down(v, (unsigned)off, 64);
    if ((t & 63) == 0) partial[t >> 6] = v;
    __syncthreads();
    if (t == 0) inv_sh = 1.0f / (partial[0] + partial[1] + partial[2] + partial[3] + 1e-8f);
    __syncthreads();
    if (t < HH)
        attn[(size_t)row * HH + t] = s * inv_sh;
}

extern "C" void kernel_launch(void* const* d_in, const int* in_sizes, int n_in,
                              void* d_out, int out_size, void* d_ws, size_t ws_size,
                              hipStream_t stream) {
    const float* Q   = (const float*)d_in[0];
    const float* K   = (const float*)d_in[1];
    const float* V   = (const float*)d_in[2];
    const float* cdd = (const float*)d_in[3];
    const float* W   = (const float*)d_in[4];
    const float* b   = (const float*)d_in[5];
    const float* W1  = (const float*)d_in[6];
    const float* b1  = (const float*)d_in[7];
    // d_in[8] = d_k (int) — compile-time constant 20

    float* proj = (float*)d_ws;           // 4*4000*20 = 320000 floats = 1.28 MB

    float* out      = (float*)d_out;
    float* ctx_out  = out;                // 80000 fp32 (context)
    float* attn_out = out + 80000;        // 800000 fp32 (attn)

    proj_kernel<<<(4 * NPOS * 5 + 255) / 256, 256, 0, stream>>>(
        Q, K, V, cdd, W, b, W1, b1, proj);
    attn_kernel<<<CC * BB * 25, 256, 0, stream>>>(proj, attn_out, ctx_out);
    norm_kernel<<<NPOS, 256, 0, stream>>>(attn_out);
}